// Round 1
// baseline (1416.530 us; speedup 1.0000x reference)
//
#include <hip/hip_runtime.h>

// DPO forward: out = log(2) + NLL(first half of batch)
//   - pref_loss is exactly log(2) in fwd (stop_gradient is identity)
//   - only rows 0..1023 of x (chosen batches) matter
// GEMM: logits[m,n] = sum_k x[m,k] * W[n,k],  M=1024, N=32000, K=4096
// Fused online: per-token sum(exp(logit)) via global atomics + target-logit scatter.

#define IGNORE_INDEX (-100)

typedef __attribute__((ext_vector_type(8))) short short8;
typedef __attribute__((ext_vector_type(4))) float f32x4;

constexpr int Ktot = 4096;
constexpr int BM = 128, BN = 128, BK = 32;
constexpr int NTILES = 250;   // 32000 / 128

// round-to-nearest-even fp32 -> bf16, packed pair (a -> low half, b -> high half)
__device__ __forceinline__ unsigned pack2_bf16(float a, float b) {
    unsigned ua = __float_as_uint(a);
    unsigned ub = __float_as_uint(b);
    ua += 0x7FFFu + ((ua >> 16) & 1u);
    ub += 0x7FFFu + ((ub >> 16) & 1u);
    return (ua >> 16) | (ub & 0xFFFF0000u);
}

__global__ __launch_bounds__(256, 2)
void dpo_gemm_lse(const float* __restrict__ X, const float* __restrict__ W,
                  const int* __restrict__ tgt2,   // int64 targets viewed as int pairs
                  float* __restrict__ ws_sum,     // [1024] sum of exp(logit)
                  float* __restrict__ ws_tl)      // [1024] logit at target
{
    // XCD-aware swizzle: blockIdx%8 -> XCD (round-robin dispatch assumption).
    // The 8 M-tiles sharing one N-tile (same 2MB W slab) are consecutive on one XCD.
    int b = blockIdx.x;
    int xcd  = b & 7;
    int j    = b >> 3;          // 0..255 within XCD
    int mt_b = j & 7;           // M tile 0..7
    int grp  = j >> 3;          // 0..31
    int nt_b = xcd + 8 * grp;   // N tile
    if (nt_b >= NTILES) return; // padded grid tail

    const int m0 = mt_b * BM;
    const int n0 = nt_b * BN;

    __shared__ __align__(16) unsigned As[128 * 16]; // 128 rows x 32 bf16 (as 16 uints)
    __shared__ __align__(16) unsigned Bs[128 * 16];

    const int tid = threadIdx.x;
    const int r = tid >> 1, h = tid & 1;   // staging: row r, 16-col half h

    const float* aptr = X + (size_t)(m0 + r) * Ktot + h * 16;
    const float* bptr = W + (size_t)(n0 + r) * Ktot + h * 16;

    const int lane = tid & 63;
    const int wid  = tid >> 6;
    const int wm = (wid >> 1) * 64, wn = (wid & 1) * 64;
    const int quad = lane >> 4, lq = lane & 15;

    f32x4 acc[4][4];
#pragma unroll
    for (int i = 0; i < 4; i++)
#pragma unroll
        for (int jj = 0; jj < 4; jj++)
            acc[i][jj] = (f32x4){0.f, 0.f, 0.f, 0.f};

    for (int kk = 0; kk < Ktot; kk += BK) {
        // global fp32 loads (16 floats each for A and B per thread)
        const float4* ap = (const float4*)(aptr + kk);
        const float4* bp = (const float4*)(bptr + kk);
        float4 a0 = ap[0], a1 = ap[1], a2 = ap[2], a3 = ap[3];
        float4 b0 = bp[0], b1 = bp[1], b2 = bp[2], b3 = bp[3];

        __syncthreads();   // previous tile fully consumed

        uint4 pa0, pa1, pb0, pb1;
        pa0.x = pack2_bf16(a0.x, a0.y); pa0.y = pack2_bf16(a0.z, a0.w);
        pa0.z = pack2_bf16(a1.x, a1.y); pa0.w = pack2_bf16(a1.z, a1.w);
        pa1.x = pack2_bf16(a2.x, a2.y); pa1.y = pack2_bf16(a2.z, a2.w);
        pa1.z = pack2_bf16(a3.x, a3.y); pa1.w = pack2_bf16(a3.z, a3.w);
        pb0.x = pack2_bf16(b0.x, b0.y); pb0.y = pack2_bf16(b0.z, b0.w);
        pb0.z = pack2_bf16(b1.x, b1.y); pb0.w = pack2_bf16(b1.z, b1.w);
        pb1.x = pack2_bf16(b2.x, b2.y); pb1.y = pack2_bf16(b2.z, b2.w);
        pb1.z = pack2_bf16(b3.x, b3.y); pb1.w = pack2_bf16(b3.z, b3.w);

        *(uint4*)&As[r * 16 + h * 8]     = pa0;
        *(uint4*)&As[r * 16 + h * 8 + 4] = pa1;
        *(uint4*)&Bs[r * 16 + h * 8]     = pb0;
        *(uint4*)&Bs[r * 16 + h * 8 + 4] = pb1;

        __syncthreads();

        short8 af[4], bf[4];
#pragma unroll
        for (int mt = 0; mt < 4; mt++)
            af[mt] = __builtin_bit_cast(short8,
                *(const uint4*)&As[(wm + mt * 16 + lq) * 16 + quad * 4]);
#pragma unroll
        for (int nt = 0; nt < 4; nt++)
            bf[nt] = __builtin_bit_cast(short8,
                *(const uint4*)&Bs[(wn + nt * 16 + lq) * 16 + quad * 4]);

#pragma unroll
        for (int mt = 0; mt < 4; mt++)
#pragma unroll
            for (int nt = 0; nt < 4; nt++)
                acc[mt][nt] = __builtin_amdgcn_mfma_f32_16x16x32_bf16(
                    af[mt], bf[nt], acc[mt][nt], 0, 0, 0);
    }

    // Epilogue: per-row sum(exp) over this wave's 64 cols, + target-logit scatter.
    // C/D layout (16x16x32 bf16): col = lane&15, row = quad*4 + reg.
#pragma unroll
    for (int mt = 0; mt < 4; mt++) {
#pragma unroll
        for (int rr = 0; rr < 4; rr++) {
            float s = __expf(acc[mt][0][rr]) + __expf(acc[mt][1][rr]) +
                      __expf(acc[mt][2][rr]) + __expf(acc[mt][3][rr]);
            s += __shfl_xor(s, 1);
            s += __shfl_xor(s, 2);
            s += __shfl_xor(s, 4);
            s += __shfl_xor(s, 8);
            const int row = m0 + wm + mt * 16 + quad * 4 + rr;
            if (lq == 0) atomicAdd(&ws_sum[row], s);
            const int tv = tgt2[2 * row];  // low word of little-endian int64
#pragma unroll
            for (int nt = 0; nt < 4; nt++) {
                const int col = n0 + wn + nt * 16 + lq;
                if (col == tv) ws_tl[row] = acc[mt][nt][rr];  // unique writer
            }
        }
    }
}

__global__ void dpo_finalize(const float* __restrict__ ws_sum,
                             const float* __restrict__ ws_tl,
                             const int* __restrict__ tgt2,
                             float* __restrict__ out)
{
    __shared__ float sred[4];
    __shared__ float cred[4];
    float s = 0.f, c = 0.f;
    for (int i = threadIdx.x; i < 1024; i += 256) {
        const int tv = tgt2[2 * i];
        if (tv != IGNORE_INDEX) {
            s += ws_tl[i] - logf(ws_sum[i]);
            c += 1.f;
        }
    }
#pragma unroll
    for (int o = 32; o > 0; o >>= 1) {
        s += __shfl_down(s, o);
        c += __shfl_down(c, o);
    }
    const int wv = threadIdx.x >> 6, lane = threadIdx.x & 63;
    if (lane == 0) { sred[wv] = s; cred[wv] = c; }
    __syncthreads();
    if (threadIdx.x == 0) {
        const float st = sred[0] + sred[1] + sred[2] + sred[3];
        const float ct = cred[0] + cred[1] + cred[2] + cred[3];
        out[0] = 0.69314718055994531f - st / ct;
    }
}

extern "C" void kernel_launch(void* const* d_in, const int* in_sizes, int n_in,
                              void* d_out, int out_size, void* d_ws, size_t ws_size,
                              hipStream_t stream) {
    const float* X    = (const float*)d_in[0];   // (4,512,4096) fp32
    const int*   tgt2 = (const int*)d_in[1];     // (4,512) int64 -> int pairs
    const float* W    = (const float*)d_in[2];   // (32000,4096) fp32
    float* out = (float*)d_out;

    float* ws_sum = (float*)d_ws;        // [1024]
    float* ws_tl  = ws_sum + 1024;       // [1024]

    hipMemsetAsync(d_ws, 0, 2048 * sizeof(float), stream);
    dpo_gemm_lse<<<2048, 256, 0, stream>>>(X, W, tgt2, ws_sum, ws_tl);
    dpo_finalize<<<1, 256, 0, stream>>>(ws_sum, ws_tl, tgt2, out);
}

// Round 2
// 1026.520 us; speedup vs baseline: 1.3799x; 1.3799x over previous
//
#include <hip/hip_runtime.h>

// DPO forward: out = log(2) + NLL(first half of batch).
// Round 2: pre-convert X/W to bf16 in ws, then m97-style GEMM with
// global_load_lds(16B) staging + segment-XOR LDS swizzle.
// Fallback to round-1 fused fp32 kernel if ws too small.

#define IGNORE_INDEX (-100)

typedef __attribute__((ext_vector_type(8))) short short8;
typedef __attribute__((ext_vector_type(4))) float f32x4;

constexpr int Ktot = 4096;
constexpr int Mtot = 1024;           // chosen-half rows only
constexpr int Vtot = 32000;
constexpr int NTILES = 250;          // 32000 / 128
constexpr long long NX = (long long)Mtot * Ktot;   // 4,194,304
constexpr long long NW = (long long)Vtot * Ktot;   // 131,072,000

__device__ __forceinline__ unsigned pack2_bf16(float a, float b) {
    unsigned ua = __float_as_uint(a);
    unsigned ub = __float_as_uint(b);
    ua += 0x7FFFu + ((ua >> 16) & 1u);
    ub += 0x7FFFu + ((ub >> 16) & 1u);
    return (ua >> 16) | (ub & 0xFFFF0000u);
}

__device__ __forceinline__ void load_lds_16(const void* g, void* l) {
    __builtin_amdgcn_global_load_lds(
        (const __attribute__((address_space(1))) unsigned int*)g,
        (__attribute__((address_space(3))) unsigned int*)l, 16, 0, 0);
}

// ---------------- fp32 -> bf16 conversion (X first 1024 rows, then W) -------
__global__ __launch_bounds__(256)
void convert_to_bf16(const float* __restrict__ X, const float* __restrict__ W,
                     unsigned short* __restrict__ Xb, unsigned short* __restrict__ Wb)
{
    long long i = ((long long)blockIdx.x * 256 + threadIdx.x) * 8;
    const float* src;
    unsigned short* dst;
    long long off;
    if (i < NX) { src = X; dst = Xb; off = i; }
    else        { src = W; dst = Wb; off = i - NX; }
    float4 v0 = *(const float4*)(src + off);
    float4 v1 = *(const float4*)(src + off + 4);
    uint4 p;
    p.x = pack2_bf16(v0.x, v0.y);
    p.y = pack2_bf16(v0.z, v0.w);
    p.z = pack2_bf16(v1.x, v1.y);
    p.w = pack2_bf16(v1.z, v1.w);
    *(uint4*)(dst + off) = p;
}

// ---------------- m97-style bf16 GEMM + fused LSE ---------------------------
__global__ __launch_bounds__(256, 2)
void gemm_lse_bf16(const unsigned short* __restrict__ Xb,
                   const unsigned short* __restrict__ Wb,
                   const int* __restrict__ tgt2,
                   float* __restrict__ ws_sum, float* __restrict__ ws_tl)
{
    // XCD swizzle: 8 M-tiles of one N-tile land consecutively on one XCD.
    int b = blockIdx.x;
    int xcd  = b & 7;
    int j    = b >> 3;
    int mt_b = j & 7;
    int grp  = j >> 3;
    int nt_b = xcd + 8 * grp;
    if (nt_b >= NTILES) return;

    const int m0 = mt_b * 128;
    const int n0 = nt_b * 128;

    __shared__ __align__(16) unsigned short As[128 * 32]; // 8 KB
    __shared__ __align__(16) unsigned short Bs[128 * 32]; // 8 KB

    const int tid  = threadIdx.x;
    const int srow = tid >> 2;           // 0..63 (staging row, this half)
    const int sseg = tid & 3;            // 16B segment slot in LDS row
    const int gseg = sseg ^ (srow & 3);  // XOR-swizzled global segment

    const unsigned short* aG = Xb + (size_t)(m0 + srow) * Ktot + gseg * 8;
    const unsigned short* bG = Wb + (size_t)(n0 + srow) * Ktot + gseg * 8;
    unsigned short* aL = As + srow * 32 + sseg * 8;   // byte off = tid*16 (wave-contig)
    unsigned short* bL = Bs + srow * 32 + sseg * 8;

    const int lane = tid & 63;
    const int wid  = tid >> 6;
    const int wm = (wid >> 1) * 64, wn = (wid & 1) * 64;
    const int quad = lane >> 4, lq = lane & 15;
    const int rseg = (quad ^ (lq & 3)) * 8;   // un-swizzled read segment

    f32x4 acc[4][4];
#pragma unroll
    for (int i = 0; i < 4; i++)
#pragma unroll
        for (int jj = 0; jj < 4; jj++)
            acc[i][jj] = (f32x4){0.f, 0.f, 0.f, 0.f};

    constexpr size_t halfjump = (size_t)64 * Ktot;  // rows 64..127

    for (int kk = 0; kk < Ktot; kk += 32) {
        __syncthreads();                      // previous tile fully consumed
        load_lds_16(aG + kk,            aL);
        load_lds_16(aG + kk + halfjump, aL + 64 * 32);
        load_lds_16(bG + kk,            bL);
        load_lds_16(bG + kk + halfjump, bL + 64 * 32);
        __syncthreads();                      // vmcnt(0) drain + barrier

        short8 af[4], bf[4];
#pragma unroll
        for (int mt = 0; mt < 4; mt++)
            af[mt] = *(const short8*)&As[(wm + mt * 16 + lq) * 32 + rseg];
#pragma unroll
        for (int nt = 0; nt < 4; nt++)
            bf[nt] = *(const short8*)&Bs[(wn + nt * 16 + lq) * 32 + rseg];

#pragma unroll
        for (int mt = 0; mt < 4; mt++)
#pragma unroll
            for (int nt = 0; nt < 4; nt++)
                acc[mt][nt] = __builtin_amdgcn_mfma_f32_16x16x32_bf16(
                    af[mt], bf[nt], acc[mt][nt], 0, 0, 0);
    }

    // Epilogue: per-row sum(exp) + target-logit scatter.
    // C/D layout: col = lane&15, row = quad*4 + reg (verified round 1).
#pragma unroll
    for (int mt = 0; mt < 4; mt++) {
#pragma unroll
        for (int rr = 0; rr < 4; rr++) {
            float s = __expf(acc[mt][0][rr]) + __expf(acc[mt][1][rr]) +
                      __expf(acc[mt][2][rr]) + __expf(acc[mt][3][rr]);
            s += __shfl_xor(s, 1);
            s += __shfl_xor(s, 2);
            s += __shfl_xor(s, 4);
            s += __shfl_xor(s, 8);
            const int row = m0 + wm + mt * 16 + quad * 4 + rr;
            if (lq == 0) atomicAdd(&ws_sum[row], s);
            const int tv = tgt2[2 * row];
#pragma unroll
            for (int nt = 0; nt < 4; nt++) {
                const int col = n0 + wn + nt * 16 + lq;
                if (col == tv) ws_tl[row] = acc[mt][nt][rr];
            }
        }
    }
}

// ---------------- round-1 fused fp32 kernel (fallback if ws too small) ------
__global__ __launch_bounds__(256, 2)
void dpo_gemm_lse_fb(const float* __restrict__ X, const float* __restrict__ W,
                     const int* __restrict__ tgt2,
                     float* __restrict__ ws_sum, float* __restrict__ ws_tl)
{
    int b = blockIdx.x;
    int xcd  = b & 7;
    int j    = b >> 3;
    int mt_b = j & 7;
    int grp  = j >> 3;
    int nt_b = xcd + 8 * grp;
    if (nt_b >= NTILES) return;

    const int m0 = mt_b * 128;
    const int n0 = nt_b * 128;

    __shared__ __align__(16) unsigned As[128 * 16];
    __shared__ __align__(16) unsigned Bs[128 * 16];

    const int tid = threadIdx.x;
    const int r = tid >> 1, h = tid & 1;

    const float* aptr = X + (size_t)(m0 + r) * Ktot + h * 16;
    const float* bptr = W + (size_t)(n0 + r) * Ktot + h * 16;

    const int lane = tid & 63;
    const int wid  = tid >> 6;
    const int wm = (wid >> 1) * 64, wn = (wid & 1) * 64;
    const int quad = lane >> 4, lq = lane & 15;

    f32x4 acc[4][4];
#pragma unroll
    for (int i = 0; i < 4; i++)
#pragma unroll
        for (int jj = 0; jj < 4; jj++)
            acc[i][jj] = (f32x4){0.f, 0.f, 0.f, 0.f};

    for (int kk = 0; kk < Ktot; kk += 32) {
        const float4* ap = (const float4*)(aptr + kk);
        const float4* bp = (const float4*)(bptr + kk);
        float4 a0 = ap[0], a1 = ap[1], a2 = ap[2], a3 = ap[3];
        float4 b0 = bp[0], b1 = bp[1], b2 = bp[2], b3 = bp[3];

        __syncthreads();

        uint4 pa0, pa1, pb0, pb1;
        pa0.x = pack2_bf16(a0.x, a0.y); pa0.y = pack2_bf16(a0.z, a0.w);
        pa0.z = pack2_bf16(a1.x, a1.y); pa0.w = pack2_bf16(a1.z, a1.w);
        pa1.x = pack2_bf16(a2.x, a2.y); pa1.y = pack2_bf16(a2.z, a2.w);
        pa1.z = pack2_bf16(a3.x, a3.y); pa1.w = pack2_bf16(a3.z, a3.w);
        pb0.x = pack2_bf16(b0.x, b0.y); pb0.y = pack2_bf16(b0.z, b0.w);
        pb0.z = pack2_bf16(b1.x, b1.y); pb0.w = pack2_bf16(b1.z, b1.w);
        pb1.x = pack2_bf16(b2.x, b2.y); pb1.y = pack2_bf16(b2.z, b2.w);
        pb1.z = pack2_bf16(b3.x, b3.y); pb1.w = pack2_bf16(b3.z, b3.w);

        *(uint4*)&As[r * 16 + h * 8]     = pa0;
        *(uint4*)&As[r * 16 + h * 8 + 4] = pa1;
        *(uint4*)&Bs[r * 16 + h * 8]     = pb0;
        *(uint4*)&Bs[r * 16 + h * 8 + 4] = pb1;

        __syncthreads();

        short8 af[4], bf[4];
#pragma unroll
        for (int mt = 0; mt < 4; mt++)
            af[mt] = __builtin_bit_cast(short8,
                *(const uint4*)&As[(wm + mt * 16 + lq) * 16 + quad * 4]);
#pragma unroll
        for (int nt = 0; nt < 4; nt++)
            bf[nt] = __builtin_bit_cast(short8,
                *(const uint4*)&Bs[(wn + nt * 16 + lq) * 16 + quad * 4]);

#pragma unroll
        for (int mt = 0; mt < 4; mt++)
#pragma unroll
            for (int nt = 0; nt < 4; nt++)
                acc[mt][nt] = __builtin_amdgcn_mfma_f32_16x16x32_bf16(
                    af[mt], bf[nt], acc[mt][nt], 0, 0, 0);
    }

#pragma unroll
    for (int mt = 0; mt < 4; mt++) {
#pragma unroll
        for (int rr = 0; rr < 4; rr++) {
            float s = __expf(acc[mt][0][rr]) + __expf(acc[mt][1][rr]) +
                      __expf(acc[mt][2][rr]) + __expf(acc[mt][3][rr]);
            s += __shfl_xor(s, 1);
            s += __shfl_xor(s, 2);
            s += __shfl_xor(s, 4);
            s += __shfl_xor(s, 8);
            const int row = m0 + wm + mt * 16 + quad * 4 + rr;
            if (lq == 0) atomicAdd(&ws_sum[row], s);
            const int tv = tgt2[2 * row];
#pragma unroll
            for (int nt = 0; nt < 4; nt++) {
                const int col = n0 + wn + nt * 16 + lq;
                if (col == tv) ws_tl[row] = acc[mt][nt][rr];
            }
        }
    }
}

// ---------------- finalize --------------------------------------------------
__global__ void dpo_finalize(const float* __restrict__ ws_sum,
                             const float* __restrict__ ws_tl,
                             const int* __restrict__ tgt2,
                             float* __restrict__ out)
{
    __shared__ float sred[4];
    __shared__ float cred[4];
    float s = 0.f, c = 0.f;
    for (int i = threadIdx.x; i < 1024; i += 256) {
        const int tv = tgt2[2 * i];
        if (tv != IGNORE_INDEX) {
            s += ws_tl[i] - logf(ws_sum[i]);
            c += 1.f;
        }
    }
#pragma unroll
    for (int o = 32; o > 0; o >>= 1) {
        s += __shfl_down(s, o);
        c += __shfl_down(c, o);
    }
    const int wv = threadIdx.x >> 6, lane = threadIdx.x & 63;
    if (lane == 0) { sred[wv] = s; cred[wv] = c; }
    __syncthreads();
    if (threadIdx.x == 0) {
        const float st = sred[0] + sred[1] + sred[2] + sred[3];
        const float ct = cred[0] + cred[1] + cred[2] + cred[3];
        out[0] = 0.69314718055994531f - st / ct;
    }
}

extern "C" void kernel_launch(void* const* d_in, const int* in_sizes, int n_in,
                              void* d_out, int out_size, void* d_ws, size_t ws_size,
                              hipStream_t stream) {
    const float* X    = (const float*)d_in[0];   // (4,512,4096) fp32
    const int*   tgt2 = (const int*)d_in[1];     // (4,512) int64 as int pairs
    const float* W    = (const float*)d_in[2];   // (32000,4096) fp32
    float* out = (float*)d_out;

    float* ws_sum = (float*)d_ws;                          // [1024] f32
    float* ws_tl  = ws_sum + 1024;                         // [1024] f32
    unsigned short* Xb = (unsigned short*)(ws_tl + 1024);  // [1024*4096] bf16
    unsigned short* Wb = Xb + NX;                          // [32000*4096] bf16

    const size_t need = 2048 * sizeof(float) + (size_t)(NX + NW) * 2;

    hipMemsetAsync(d_ws, 0, 2048 * sizeof(float), stream);
    if (ws_size >= need) {
        const int conv_blocks = (int)((NX + NW) / 8 / 256);  // exact: 66048
        convert_to_bf16<<<conv_blocks, 256, 0, stream>>>(X, W, Xb, Wb);
        gemm_lse_bf16<<<2048, 256, 0, stream>>>(Xb, Wb, tgt2, ws_sum, ws_tl);
    } else {
        dpo_gemm_lse_fb<<<2048, 256, 0, stream>>>(X, W, tgt2, ws_sum, ws_tl);
    }
    dpo_finalize<<<1, 256, 0, stream>>>(ws_sum, ws_tl, tgt2, out);
}